// Round 1
// 610.063 us; speedup vs baseline: 1.1022x; 1.1022x over previous
//
#include <hip/hip_runtime.h>
#include <math.h>

#define B      32
#define S      4096
#define H      1024
#define NSPANS 16
#define NCLS   25

// ---------------------------------------------------------------------------
// K1: span-mean pooling. Grid (NSPANS, B), block 256.
// Wave 0 derives validity ("break at first (0,0)") lane-parallel via ballot;
// main loop is 4-deep software-pipelined float4 accumulation to keep 4 HBM
// loads in flight per thread instead of a near-serial dynamic loop.
// ---------------------------------------------------------------------------
__global__ __launch_bounds__(256) void span_pool_kernel(
    const float* __restrict__ emb,       // [B,S,H]
    const int*   __restrict__ spans,     // [B,NSPANS,2]
    float*       __restrict__ pooled)    // [B,H]  (pre-zeroed)
{
    const int n = blockIdx.x;
    const int b = blockIdx.y;

    __shared__ int   sh_s0, sh_s1, sh_valid;
    __shared__ float sh_scale;

    if (threadIdx.x < 64) {
        const int k = threadIdx.x;
        int a = 0, e = 0;
        if (k < NSPANS) {
            a = spans[(b * NSPANS + k) * 2 + 0];
            e = spans[(b * NSPANS + k) * 2 + 1];
        }
        // lanes >= NSPANS have a=e=0 -> bit clear in nzmask
        unsigned long long nzmask = __ballot((a | e) != 0);
        // first (0,0) row == first zero bit (torch 'break' semantics)
        const int nvalid = (int)__builtin_ctzll(~nzmask);   // in [0, NSPANS]

        int len = (k < nvalid) ? (e - a) : 0;
        #pragma unroll
        for (int off = 32; off > 0; off >>= 1)
            len += __shfl_down(len, off, 64);               // lane 0: total

        if (k == 0) {
            sh_scale = (len > 0) ? (1.0f / (float)len) : 0.0f;
            sh_valid = (n < nvalid);
        }
        if (k == n) { sh_s0 = a; sh_s1 = e; }
    }
    __syncthreads();

    if (!sh_valid) return;
    const int   s0    = sh_s0;
    const int   s1    = sh_s1;
    const float scale = sh_scale;

    const float4* base = (const float4*)(emb + (size_t)b * S * H) + threadIdx.x;

    float4 a0 = make_float4(0.f, 0.f, 0.f, 0.f);
    float4 a1 = make_float4(0.f, 0.f, 0.f, 0.f);
    float4 a2 = make_float4(0.f, 0.f, 0.f, 0.f);
    float4 a3 = make_float4(0.f, 0.f, 0.f, 0.f);

    int t = s0;
    for (; t + 4 <= s1; t += 4) {
        float4 v0 = base[(size_t)(t + 0) * (H / 4)];
        float4 v1 = base[(size_t)(t + 1) * (H / 4)];
        float4 v2 = base[(size_t)(t + 2) * (H / 4)];
        float4 v3 = base[(size_t)(t + 3) * (H / 4)];
        a0.x += v0.x; a0.y += v0.y; a0.z += v0.z; a0.w += v0.w;
        a1.x += v1.x; a1.y += v1.y; a1.z += v1.z; a1.w += v1.w;
        a2.x += v2.x; a2.y += v2.y; a2.z += v2.z; a2.w += v2.w;
        a3.x += v3.x; a3.y += v3.y; a3.z += v3.z; a3.w += v3.w;
    }
    for (; t < s1; ++t) {
        float4 v = base[(size_t)t * (H / 4)];
        a0.x += v.x; a0.y += v.y; a0.z += v.z; a0.w += v.w;
    }

    a0.x += a1.x + a2.x + a3.x;
    a0.y += a1.y + a2.y + a3.y;
    a0.z += a1.z + a2.z + a3.z;
    a0.w += a1.w + a2.w + a3.w;

    float* dst = pooled + (size_t)b * H + threadIdx.x * 4;
    atomicAdd(dst + 0, a0.x * scale);
    atomicAdd(dst + 1, a0.y * scale);
    atomicAdd(dst + 2, a0.z * scale);
    atomicAdd(dst + 3, a0.w * scale);
}

// ---------------------------------------------------------------------------
// K2: h = relu(pooled @ W1 + b1).  Grid B*16 = 512 blocks of 256 threads.
// Each block: 64 outputs; wave q (of 4) covers i-quarter q. All 256 CUs get
// work (vs 128 before), per-thread dependent-FMA chain drops 1024 -> 256.
// Within a wave, 64 lanes read 64 consecutive W1 floats (coalesced, L2-hot).
// ---------------------------------------------------------------------------
__global__ __launch_bounds__(256) void fc1_relu_kernel(
    const float* __restrict__ pooled,    // [B,H]
    const float* __restrict__ W1,        // [H,H] row-major
    const float* __restrict__ b1,        // [H]
    float*       __restrict__ hbuf)      // [B,H]
{
    const int b    = blockIdx.x >> 4;            // 16 blocks per batch
    const int jblk = (blockIdx.x & 15) << 6;     // 64 outputs per block
    const int lane = threadIdx.x & 63;
    const int quad = threadIdx.x >> 6;           // wave id = i-quarter
    const int j    = jblk + lane;

    __shared__ float pool_s[H];
    ((float4*)pool_s)[threadIdx.x] =
        ((const float4*)(pooled + (size_t)b * H))[threadIdx.x];
    __syncthreads();

    const float* w = W1 + j;
    float acc = 0.0f;
    const int i0 = quad * (H / 4);
    #pragma unroll 8
    for (int i = i0; i < i0 + H / 4; ++i) {
        acc = fmaf(pool_s[i], w[(size_t)i * H], acc);
    }

    __shared__ float part[4][64];
    part[quad][lane] = acc;
    __syncthreads();

    if (threadIdx.x < 64) {
        float s = part[0][lane] + part[1][lane] + part[2][lane] + part[3][lane]
                + b1[jblk + lane];
        hbuf[(size_t)b * H + jblk + lane] = fmaxf(s, 0.0f);
    }
}

// ---------------------------------------------------------------------------
// K3: out = sigmoid(h @ W2 + b2).  Grid (NCLS, B), block 256.
// Wave shuffle reduce (width 64) then LDS across the 4 waves.
// ---------------------------------------------------------------------------
__global__ __launch_bounds__(256) void fc2_sigmoid_kernel(
    const float* __restrict__ hbuf,      // [B,H]
    const float* __restrict__ W2,        // [H,NCLS]
    const float* __restrict__ b2,        // [NCLS]
    float*       __restrict__ out)       // [B,NCLS]
{
    const int c = blockIdx.x;
    const int b = blockIdx.y;

    const float* hrow = hbuf + (size_t)b * H;
    float partial = 0.0f;
    #pragma unroll
    for (int i = threadIdx.x; i < H; i += 256) {
        partial = fmaf(hrow[i], W2[(size_t)i * NCLS + c], partial);
    }

    #pragma unroll
    for (int off = 32; off > 0; off >>= 1)
        partial += __shfl_down(partial, off, 64);

    __shared__ float wsum[4];
    const int wave = threadIdx.x >> 6;
    const int lane = threadIdx.x & 63;
    if (lane == 0) wsum[wave] = partial;
    __syncthreads();

    if (threadIdx.x == 0) {
        float s = wsum[0] + wsum[1] + wsum[2] + wsum[3] + b2[c];
        out[(size_t)b * NCLS + c] = 1.0f / (1.0f + expf(-s));
    }
}

// ---------------------------------------------------------------------------
extern "C" void kernel_launch(void* const* d_in, const int* in_sizes, int n_in,
                              void* d_out, int out_size, void* d_ws, size_t ws_size,
                              hipStream_t stream) {
    const float* emb   = (const float*)d_in[0];
    const int*   spans = (const int*)  d_in[1];
    const float* W1    = (const float*)d_in[2];
    const float* b1    = (const float*)d_in[3];
    const float* W2    = (const float*)d_in[4];
    const float* b2    = (const float*)d_in[5];
    float*       out   = (float*)d_out;

    float* pooled = (float*)d_ws;          // B*H floats = 128 KB
    float* hbuf   = pooled + B * H;        // B*H floats = 128 KB

    // pooled must start from zero (ws is poisoned with 0xAA before each call)
    hipMemsetAsync(d_ws, 0, (size_t)B * H * sizeof(float), stream);

    span_pool_kernel<<<dim3(NSPANS, B), 256, 0, stream>>>(emb, spans, pooled);
    fc1_relu_kernel<<<dim3(B * 16), 256, 0, stream>>>(pooled, W1, b1, hbuf);
    fc2_sigmoid_kernel<<<dim3(NCLS, B), 256, 0, stream>>>(hbuf, W2, b2, out);
}